// Round 12
// baseline (266.393 us; speedup 1.0000x reference)
//
#include <hip/hip_runtime.h>
#include <math.h>

#define EPS 1e-8f
#define NB_SORT 256  // blocks in coarse sort phases

#if defined(__has_builtin)
#if __has_builtin(__builtin_amdgcn_sdot4)
#define HAVE_SDOT4 1
#endif
#endif

typedef __attribute__((ext_vector_type(8))) short bf16x8;
typedef __attribute__((ext_vector_type(4))) float f32x4;

__device__ __forceinline__ int sdot4i(int a, int b, int c) {
#ifdef HAVE_SDOT4
  return __builtin_amdgcn_sdot4(a, b, c, false);
#else
  return c + ((int)(signed char)(a)) * ((int)(signed char)(b)) +
         ((int)(signed char)(a >> 8)) * ((int)(signed char)(b >> 8)) +
         ((int)(signed char)(a >> 16)) * ((int)(signed char)(b >> 16)) +
         (a >> 24) * (b >> 24);
#endif
}

__device__ __forceinline__ float wave_reduce_sum(float v) {
#pragma unroll
  for (int off = 32; off > 0; off >>= 1)
    v += __shfl_xor(v, off, 64);
  return v;
}

__device__ __forceinline__ float wave_reduce_max(float v) {
#pragma unroll
  for (int off = 32; off > 0; off >>= 1)
    v = fmaxf(v, __shfl_xor(v, off, 64));
  return v;
}

__device__ __forceinline__ float dot4(float4 a, float4 b) {
  return a.x * b.x + a.y * b.y + a.z * b.z + a.w * b.w;
}

__device__ __forceinline__ int clampq(float q) {
  int i = (int)rintf(q);
  return i < -127 ? -127 : (i > 127 ? 127 : i);
}

// split fp32 into bf16 hi (truncate) + bf16 lo (exact residual, truncate)
// |x - (hi+lo)| <= 2^-16 |x|  (residual x-hi is exactly representable)
__device__ __forceinline__ void split_bf16(float x, unsigned int& hi,
                                           unsigned int& lo) {
  unsigned int u = __float_as_uint(x);
  hi = u >> 16;
  float hf = __uint_as_float(u & 0xFFFF0000u);
  float r = x - hf;
  lo = __float_as_uint(r) >> 16;
}

// split 8 fp32 (two float4) into bf16x8 hi/lo fragments
__device__ __forceinline__ void split8(float4 a0, float4 a1, bf16x8& th,
                                       bf16x8& tl) {
  unsigned int hh[8], ll[8];
  split_bf16(a0.x, hh[0], ll[0]); split_bf16(a0.y, hh[1], ll[1]);
  split_bf16(a0.z, hh[2], ll[2]); split_bf16(a0.w, hh[3], ll[3]);
  split_bf16(a1.x, hh[4], ll[4]); split_bf16(a1.y, hh[5], ll[5]);
  split_bf16(a1.z, hh[6], ll[6]); split_bf16(a1.w, hh[7], ll[7]);
#pragma unroll
  for (int j = 0; j < 8; ++j) {
    th[j] = (short)hh[j];
    tl[j] = (short)ll[j];
  }
}

// ============ CSR build: 2-level bucket sort, LDS atomics only ============
__global__ __launch_bounds__(256) void hist_coarse(const int* __restrict__ dst,
                                                   int* __restrict__ hist_blk,
                                                   int E, int nbuck) {
  __shared__ int lh[1024];
  int t = threadIdx.x, blk = blockIdx.x;
  for (int i = t; i < nbuck; i += 256) lh[i] = 0;
  __syncthreads();
  int ch = (E + NB_SORT - 1) / NB_SORT;
  int lo = blk * ch, hi = min(E, lo + ch);
  for (int e = lo + t; e < hi; e += 256) atomicAdd(&lh[dst[e] >> 6], 1);
  __syncthreads();
  for (int i = t; i < nbuck; i += 256) hist_blk[i * NB_SORT + blk] = lh[i];
}

__global__ __launch_bounds__(256) void scan_local(int* __restrict__ hist,
                                                  int* __restrict__ bsum,
                                                  int nb) {
  __shared__ int tsum[256];
  int t = threadIdx.x;
  int base = blockIdx.x * 1024 + t * 4;
  int v0 = 0, v1 = 0, v2 = 0, v3 = 0;
  if (base + 3 < nb) {
    int4 q = *(const int4*)&hist[base];
    v0 = q.x; v1 = q.y; v2 = q.z; v3 = q.w;
  } else {
    if (base + 0 < nb) v0 = hist[base + 0];
    if (base + 1 < nb) v1 = hist[base + 1];
    if (base + 2 < nb) v2 = hist[base + 2];
  }
  tsum[t] = v0 + v1 + v2 + v3;
  __syncthreads();
  for (int off = 1; off < 256; off <<= 1) {
    int u = 0;
    if (t >= off) u = tsum[t - off];
    __syncthreads();
    if (t >= off) tsum[t] += u;
    __syncthreads();
  }
  int excl = (t == 0) ? 0 : tsum[t - 1];
  int e0 = excl, e1 = excl + v0, e2 = e1 + v1, e3 = e2 + v2;
  if (base + 3 < nb) {
    *(int4*)&hist[base] = make_int4(e0, e1, e2, e3);
  } else {
    if (base + 0 < nb) hist[base + 0] = e0;
    if (base + 1 < nb) hist[base + 1] = e1;
    if (base + 2 < nb) hist[base + 2] = e2;
  }
  if (t == 255) bsum[blockIdx.x] = tsum[255];
}

__global__ __launch_bounds__(256) void scan_bsum(int* __restrict__ bsum,
                                                 int nblk) {
  __shared__ int sh[256];
  int t = threadIdx.x;
  sh[t] = (t < nblk) ? bsum[t] : 0;
  __syncthreads();
  for (int off = 1; off < 256; off <<= 1) {
    int u = 0;
    if (t >= off) u = sh[t - off];
    __syncthreads();
    if (t >= off) sh[t] += u;
    __syncthreads();
  }
  if (t < nblk) bsum[t] = (t == 0) ? 0 : sh[t - 1];
}

__global__ __launch_bounds__(256) void add_bsum(int* __restrict__ hist,
                                                const int* __restrict__ bsum,
                                                int nb) {
  int i = blockIdx.x * blockDim.x + threadIdx.x;
  if (i < nb) hist[i] += bsum[i >> 10];
}

__global__ __launch_bounds__(256) void scatter_coarse(
    const int* __restrict__ src, const int* __restrict__ dst,
    const int* __restrict__ S, int2* __restrict__ epair, int E, int nbuck) {
  __shared__ int lb[1024];
  int t = threadIdx.x, blk = blockIdx.x;
  for (int i = t; i < nbuck; i += 256) lb[i] = S[i * NB_SORT + blk];
  __syncthreads();
  int ch = (E + NB_SORT - 1) / NB_SORT;
  int lo = blk * ch, hi = min(E, lo + ch);
  for (int e = lo + t; e < hi; e += 256) {
    int d = dst[e];
    int pos = atomicAdd(&lb[d >> 6], 1);
    epair[pos] = make_int2(src[e], d);
  }
}

// emits fully dst-sorted (src,dst) pairs
__global__ __launch_bounds__(256) void fine_sort(
    const int2* __restrict__ epair, const int* __restrict__ S,
    int2* __restrict__ spair, int E, int nbuck) {
  __shared__ int fh[64];
  __shared__ int cur[64];
  int b = blockIdx.x, t = threadIdx.x;
  int bstart = S[b * NB_SORT];
  int bend = (b + 1 < nbuck) ? S[(b + 1) * NB_SORT] : E;
  if (t < 64) fh[t] = 0;
  __syncthreads();
  for (int e = bstart + t; e < bend; e += 256)
    atomicAdd(&fh[epair[e].y & 63], 1);
  __syncthreads();
  if (t < 64) {
    int v = fh[t];
    int incl = v;
#pragma unroll
    for (int off = 1; off < 64; off <<= 1) {
      int u = __shfl_up(incl, off, 64);
      if (t >= off) incl += u;
    }
    cur[t] = incl - v;
  }
  __syncthreads();
  for (int e = bstart + t; e < bend; e += 256) {
    int2 p = epair[e];
    int pos = atomicAdd(&cur[p.y & 63], 1);
    spair[bstart + pos] = p;
  }
}

// ============ prep_x: quantize + node props + self-loop agg init ==========
__global__ __launch_bounds__(256) void prep_x(const float* __restrict__ x,
                                              signed char* __restrict__ qx,
                                              float4* __restrict__ nprop,
                                              float* __restrict__ agg,
                                              int N) {
  int node = (int)((blockIdx.x * blockDim.x + threadIdx.x) >> 6);
  int lane = threadIdx.x & 63;
  if (node >= N) return;
  float2 v = *(const float2*)(x + (size_t)node * 128 + lane * 2);
  float ax = fabsf(v.x), ay = fabsf(v.y);
  float mx = wave_reduce_max(fmaxf(ax, ay));
  float l1 = wave_reduce_sum(ax + ay);
  float ss = wave_reduce_sum(v.x * v.x + v.y * v.y);
  float s = mx * (1.0f / 127.0f);
  float inv = (mx > 0.f) ? 127.0f / mx : 0.f;
  int q0 = clampq(v.x * inv), q1 = clampq(v.y * inv);
  unsigned short w = (unsigned short)((q0 & 0xff) | ((q1 & 0xff) << 8));
  ((unsigned short*)(qx + (size_t)node * 128))[lane] = w;
  float l1q = s * wave_reduce_sum((float)(abs(q0) + abs(q1)));
  bool sp = ss > 0.5f * fmaxf(ss, EPS);
  *(float2*)(agg + (size_t)node * 128 + lane * 2) =
      sp ? v : make_float2(0.f, 0.f);
  if (lane == 0)
    nprop[node] = make_float4(sqrtf(ss), s, fmaxf(l1, l1q), 0.f);
}

// ====== conv, group-cooperative + edge-batched: G = D/16 lanes per edge ====
// B=4 consecutive edge-groups per wave: all 2B qt-row loads (+nprop) issued
// back-to-back before any compute -> 4x the independent cache lines in
// flight per wave, 4x fewer blocks. Per-edge decision math is unchanged.
template <int D, int B>
__global__ __launch_bounds__(256) void conv_coop(
    const float* __restrict__ xf, const signed char* __restrict__ qt,
    const float4* __restrict__ nprop, const int2* __restrict__ spair,
    float* __restrict__ agg, int E) {
  constexpr int G = D / 16;    // lanes per edge: 8 (D=128) / 16 (D=256)
  constexpr int EPW = 64 / G;  // edges per wave per batch: 8 / 4
  constexpr int V = D / 64;    // fp32 elems per lane, full-wave path
  const int tid = threadIdx.x;
  const int lane = tid & 63;
  const int wv = tid >> 6;
  const int g = lane & (G - 1);
  const int sub = lane / G;
  const int w0 = (blockIdx.x * 4 + wv) * (EPW * B);
  int sA[B], dA[B];
  bool valA[B];
  float4 npsA[B], npdA[B];
  int4 qa[B], qb[B];
#pragma unroll
  for (int b = 0; b < B; ++b) {
    int e = w0 + b * EPW + sub;
    valA[b] = e < E;
    int2 p = spair[valA[b] ? e : (E - 1)];
    sA[b] = p.x;
    dA[b] = p.y;
  }
#pragma unroll
  for (int b = 0; b < B; ++b) {
    npsA[b] = nprop[sA[b]];
    npdA[b] = nprop[dA[b]];
    qa[b] = *(const int4*)(qt + (size_t)sA[b] * D + g * 16);
    qb[b] = *(const int4*)(qt + (size_t)dA[b] * D + g * 16);
  }
#pragma unroll
  for (int b = 0; b < B; ++b) {
    const int s = sA[b], d = dA[b];
    const float4 nps = npsA[b], npd = npdA[b];
    int id = 0;
    id = sdot4i(qa[b].x, qb[b].x, id);
    id = sdot4i(qa[b].y, qb[b].y, id);
    id = sdot4i(qa[b].z, qb[b].z, id);
    id = sdot4i(qa[b].w, qb[b].w, id);
#pragma unroll
    for (int off = G / 2; off > 0; off >>= 1) id += __shfl_xor(id, off, 64);
    float denom = fmaxf(nps.x * npd.x, EPS);
    float thr = 0.5f * denom;
    float approx = (nps.y * npd.y) * (float)id;
    float m =
        0.5002f * (nps.y * npd.z + npd.y * nps.z) + 2e-6f * denom + 1e-7f;
    bool maybe = valA[b] && (approx > thr - m);
    bool defp = maybe && (approx - m > thr);  // certainly above threshold
    bool amb = maybe && !defp;                // needs exact recompute
    unsigned long long defmask = __ballot(defp && g == 0);
    unsigned long long ambmask = __ballot(amb && g == 0);
    // ---- definite passes: add xf[src] into agg[dst], no dot needed ----
    while (defmask) {
      int ln = __ffsll((long long)defmask) - 1;
      defmask &= defmask - 1;
      int es = __shfl(s, ln);
      int ed = __shfl(d, ln);
      float* arow = agg + (size_t)ed * D + lane * V;
      if constexpr (V == 2) {
        float2 a = *(const float2*)(xf + (size_t)es * D + lane * 2);
        atomicAdd(&arow[0], a.x);
        atomicAdd(&arow[1], a.y);
      } else {
        float4 a = *(const float4*)(xf + (size_t)es * D + lane * 4);
        atomicAdd(&arow[0], a.x);
        atomicAdd(&arow[1], a.y);
        atomicAdd(&arow[2], a.z);
        atomicAdd(&arow[3], a.w);
      }
    }
    // ---- ambiguous: full-wave exact fp32 check (unchanged math) ----
    while (ambmask) {
      int ln = __ffsll((long long)ambmask) - 1;
      ambmask &= ambmask - 1;
      int es = __shfl(s, ln);
      int ed = __shfl(d, ln);
      float nsx = __shfl(nps.x, ln);
      float ndx = __shfl(npd.x, ln);
      float sv[V], dvv[V];
      if constexpr (V == 2) {
        float2 a = *(const float2*)(xf + (size_t)es * D + lane * 2);
        float2 bb = *(const float2*)(xf + (size_t)ed * D + lane * 2);
        sv[0] = a.x; sv[1] = a.y; dvv[0] = bb.x; dvv[1] = bb.y;
      } else {
        float4 a = *(const float4*)(xf + (size_t)es * D + lane * 4);
        float4 bb = *(const float4*)(xf + (size_t)ed * D + lane * 4);
        sv[0] = a.x; sv[1] = a.y; sv[2] = a.z; sv[3] = a.w;
        dvv[0] = bb.x; dvv[1] = bb.y; dvv[2] = bb.z; dvv[3] = bb.w;
      }
      float dx = 0.f;
#pragma unroll
      for (int q = 0; q < V; ++q) dx += sv[q] * dvv[q];
      dx = wave_reduce_sum(dx);
      if (dx > 0.5f * fmaxf(nsx * ndx, EPS)) {
        float* arow = agg + (size_t)ed * D + lane * V;
#pragma unroll
        for (int q = 0; q < V; ++q) atomicAdd(&arow[q], sv[q]);
      }
    }
  }
}

// ---- pre-split BOTH weight matrices into bf16 hi/lo planes (one launch) ---
__global__ __launch_bounds__(256) void split_w2x(
    const float* __restrict__ W2, unsigned short* __restrict__ W2h,
    unsigned short* __restrict__ W2l, const float* __restrict__ W1,
    unsigned short* __restrict__ W1h, unsigned short* __restrict__ W1l) {
  int blk = blockIdx.x;
  const float* W;
  unsigned short *Wh, *Wl;
  int i;
  if (blk < 16) {  // W2: 64*256/4 = 4096 float4 = 16 blocks
    W = W2; Wh = W2h; Wl = W2l;
    i = blk * 256 + threadIdx.x;
  } else {  // W1: 256*128/4 = 8192 float4 = 32 blocks
    W = W1; Wh = W1h; Wl = W1l;
    i = (blk - 16) * 256 + threadIdx.x;
  }
  float4 w = ((const float4*)W)[i];
  unsigned int h0, h1, h2, h3, l0, l1, l2, l3;
  split_bf16(w.x, h0, l0); split_bf16(w.y, h1, l1);
  split_bf16(w.z, h2, l2); split_bf16(w.w, h3, l3);
  ((uint2*)Wh)[i] = make_uint2(h0 | (h1 << 16), h2 | (h3 << 16));
  ((uint2*)Wl)[i] = make_uint2(l0 | (l1 << 16), l2 | (l3 << 16));
}

// ------ GEMM1 + prep_h FUSED, coalesced NONTEMPORAL epilogue ---------------
// Identical math/layout to round 10 (passing, WRITE=113MB). The 113MB of
// h/agg2/qh output cannot fit L2 and is consumed much later -> nontemporal
// stores keep it out of L2, freeing it for the A-read stream. NT stores go
// through ext-vector f32x4 (clang's builtin rejects HIP_vector_type).
__global__ __launch_bounds__(256) void gemm1_prep_fused(
    const float* __restrict__ A, const unsigned short* __restrict__ Wh,
    const unsigned short* __restrict__ Wl, const float* __restrict__ bias,
    float* __restrict__ h, signed char* __restrict__ qh,
    float4* __restrict__ nprop, float* __restrict__ agg2, int M, int nwg) {
  constexpr int K = 128, NN = 256, PAD = 68;
  // bijective XCD swizzle (m204)
  int orig = blockIdx.x;
  int qq = nwg >> 3, rr8 = nwg & 7;
  int xcd = orig & 7, loc = orig >> 3;
  int wg = (xcd < rr8 ? xcd * (qq + 1) : rr8 * (qq + 1) + (xcd - rr8) * qq) + loc;
  const int tid = threadIdx.x;
  const int lane = tid & 63;
  const int wv = tid >> 6;  // wave = 64-col slice
  const int lrow = lane & 15, kg = lane >> 4;
  const int r0 = wg * 32;
  const int n0 = wv * 64;
  __shared__ float stage[4][32][PAD];  // 34816 B, per-wave 32x64 slice
  __shared__ float4 red[32][4];        // per-row per-wave (mx, ss, l1, -)
  __shared__ float4 state[32];         // per-row (ss, s, inv, l1)
  __shared__ float red2[32][4];        // per-row per-wave sum|q|

  f32x4 acc[2][4] = {};
  for (int k0 = 0; k0 < K; k0 += 32) {
    bf16x8 ah[2], al[2];
#pragma unroll
    for (int m = 0; m < 2; ++m) {
      int row = r0 + m * 16 + lrow;  // rows < 50016 stay inside ws
      const float* ap = A + (size_t)row * K + k0 + kg * 8;
      float4 a0 = *(const float4*)ap;
      float4 a1 = *(const float4*)(ap + 4);
      split8(a0, a1, ah[m], al[m]);
    }
    bf16x8 bh[4], bl[4];
#pragma unroll
    for (int n = 0; n < 4; ++n) {
      int wrow = n0 + n * 16 + lrow;
      bh[n] = *(const bf16x8*)&Wh[(size_t)wrow * K + k0 + kg * 8];
      bl[n] = *(const bf16x8*)&Wl[(size_t)wrow * K + k0 + kg * 8];
    }
#pragma unroll
    for (int m = 0; m < 2; ++m)
#pragma unroll
      for (int n = 0; n < 4; ++n) {
        acc[m][n] = __builtin_amdgcn_mfma_f32_16x16x32_bf16(ah[m], bh[n],
                                                            acc[m][n], 0, 0, 0);
        acc[m][n] = __builtin_amdgcn_mfma_f32_16x16x32_bf16(ah[m], bl[n],
                                                            acc[m][n], 0, 0, 0);
        acc[m][n] = __builtin_amdgcn_mfma_f32_16x16x32_bf16(al[m], bh[n],
                                                            acc[m][n], 0, 0, 0);
      }
  }

  // ---- bias + relu in place ----
  float bv[4];
#pragma unroll
  for (int n = 0; n < 4; ++n) bv[n] = bias[n0 + n * 16 + lrow];
#pragma unroll
  for (int m = 0; m < 2; ++m)
#pragma unroll
    for (int n = 0; n < 4; ++n)
#pragma unroll
      for (int r = 0; r < 4; ++r)
        acc[m][n][r] = fmaxf(acc[m][n][r] + bv[n], 0.f);

  // ---- per-row partials within wave (row = m*16 + kg*4 + r) ----
#pragma unroll
  for (int m = 0; m < 2; ++m)
#pragma unroll
    for (int r = 0; r < 4; ++r) {
      float mx = 0.f, ss = 0.f, l1 = 0.f;
#pragma unroll
      for (int n = 0; n < 4; ++n) {
        float v = acc[m][n][r];
        float a = fabsf(v);
        mx = fmaxf(mx, a);
        ss += v * v;
        l1 += a;
      }
#pragma unroll
      for (int off = 1; off < 16; off <<= 1) {
        mx = fmaxf(mx, __shfl_xor(mx, off, 64));
        ss += __shfl_xor(ss, off, 64);
        l1 += __shfl_xor(l1, off, 64);
      }
      if (lrow == 0) red[m * 16 + kg * 4 + r][wv] = make_float4(mx, ss, l1, 0.f);
    }

  // ---- stage the wave's 32x64 slice into LDS (2-way banks = free) ----
#pragma unroll
  for (int m = 0; m < 2; ++m)
#pragma unroll
    for (int n = 0; n < 4; ++n)
#pragma unroll
      for (int r = 0; r < 4; ++r)
        stage[wv][m * 16 + kg * 4 + r][n * 16 + lrow] = acc[m][n][r];

  __syncthreads();
  if (tid < 32) {
    float mx = 0.f, ss = 0.f, l1 = 0.f;
#pragma unroll
    for (int w = 0; w < 4; ++w) {
      float4 p = red[tid][w];
      mx = fmaxf(mx, p.x);
      ss += p.y;
      l1 += p.z;
    }
    float s = mx * (1.0f / 127.0f);
    float inv = (mx > 0.f) ? 127.0f / mx : 0.f;
    state[tid] = make_float4(ss, s, inv, l1);
  }
  __syncthreads();

  // ---- coalesced nontemporal stores: 4 rows x contiguous 256B / instr ----
  {
    const int rr = lane >> 4;   // row within quad
    const int cc = lane & 15;   // col group (4 floats)
#pragma unroll
    for (int rb = 0; rb < 8; ++rb) {
      const int row = rb * 4 + rr;
      const int grow = r0 + row;
      const bool ok = grow < M;
      float4 st = state[row];
      float inv = st.z;
      float spm = (st.x > 0.5f * fmaxf(st.x, EPS)) ? 1.0f : 0.0f;
      f32x4 v4 = *(const f32x4*)&stage[wv][row][cc * 4];
      int q0 = clampq(v4[0] * inv), q1 = clampq(v4[1] * inv);
      int q2 = clampq(v4[2] * inv), q3 = clampq(v4[3] * inv);
      int sq = abs(q0) + abs(q1) + abs(q2) + abs(q3);
#pragma unroll
      for (int off = 1; off < 16; off <<= 1) sq += __shfl_xor(sq, off, 64);
      if (ok) {
        int col = n0 + cc * 4;
        __builtin_nontemporal_store(v4, (f32x4*)&h[(size_t)grow * NN + col]);
        f32x4 a4 = v4 * spm;
        __builtin_nontemporal_store(a4,
                                    (f32x4*)&agg2[(size_t)grow * NN + col]);
        int packed = (q0 & 0xff) | ((q1 & 0xff) << 8) | ((q2 & 0xff) << 16) |
                     (q3 << 24);
        __builtin_nontemporal_store(packed, (int*)&qh[(size_t)grow * NN + col]);
      }
      if (cc == 0) red2[row][wv] = (float)sq;
    }
  }
  __syncthreads();
  if (tid < 32) {
    float sq = 0.f;
#pragma unroll
    for (int w = 0; w < 4; ++w) sq += red2[tid][w];
    float4 st = state[tid];
    float l1q = st.y * sq;
    int grow = r0 + tid;
    if (grow < M)
      nprop[grow] = make_float4(sqrtf(st.x), st.y, fmaxf(st.w, l1q), 0.f);
  }
}

// ------ GEMM2 via MFMA, LDS-free, fused log_softmax ------------------------
__global__ __launch_bounds__(256) void gemm2_mfma_lsm(
    const float* __restrict__ A, const unsigned short* __restrict__ Wh,
    const unsigned short* __restrict__ Wl, const float* __restrict__ bias,
    float* __restrict__ out, int M) {
  constexpr int K = 256;
  const int tid = threadIdx.x;
  const int lane = tid & 63;
  const int wv = tid >> 6;
  const int lrow = lane & 15, kg = lane >> 4;
  const int r0 = blockIdx.x * 128 + wv * 32;  // wave's first row
  f32x4 acc[2][4] = {};

  for (int k0 = 0; k0 < K; k0 += 32) {
    bf16x8 ah[2], al[2];
#pragma unroll
    for (int m = 0; m < 2; ++m) {
      int row = r0 + m * 16 + lrow;  // rows up to 50047 stay inside ws
      const float* ap = A + (size_t)row * K + k0 + kg * 8;
      float4 a0 = *(const float4*)ap;
      float4 a1 = *(const float4*)(ap + 4);
      split8(a0, a1, ah[m], al[m]);
    }
    bf16x8 bh[4], bl[4];
#pragma unroll
    for (int n = 0; n < 4; ++n) {
      int wrow = n * 16 + lrow;
      bh[n] = *(const bf16x8*)&Wh[(size_t)wrow * K + k0 + kg * 8];
      bl[n] = *(const bf16x8*)&Wl[(size_t)wrow * K + k0 + kg * 8];
    }
#pragma unroll
    for (int m = 0; m < 2; ++m)
#pragma unroll
      for (int n = 0; n < 4; ++n) {
        acc[m][n] = __builtin_amdgcn_mfma_f32_16x16x32_bf16(ah[m], bh[n],
                                                            acc[m][n], 0, 0, 0);
        acc[m][n] = __builtin_amdgcn_mfma_f32_16x16x32_bf16(ah[m], bl[n],
                                                            acc[m][n], 0, 0, 0);
        acc[m][n] = __builtin_amdgcn_mfma_f32_16x16x32_bf16(al[m], bh[n],
                                                            acc[m][n], 0, 0, 0);
      }
  }

  float bv[4];
#pragma unroll
  for (int n = 0; n < 4; ++n) bv[n] = bias[n * 16 + lrow];
#pragma unroll
  for (int m = 0; m < 2; ++m)
#pragma unroll
    for (int r = 0; r < 4; ++r) {
      int row = r0 + m * 16 + kg * 4 + r;
      float v[4];
      float mx = -1e30f;
#pragma unroll
      for (int n = 0; n < 4; ++n) {
        v[n] = acc[m][n][r] + bv[n];
        mx = fmaxf(mx, v[n]);
      }
#pragma unroll
      for (int off = 8; off > 0; off >>= 1)
        mx = fmaxf(mx, __shfl_xor(mx, off, 64));
      float s = 0.f;
#pragma unroll
      for (int n = 0; n < 4; ++n) s += expf(v[n] - mx);
#pragma unroll
      for (int off = 8; off > 0; off >>= 1) s += __shfl_xor(s, off, 64);
      float lg = logf(s);
      if (row < M) {
#pragma unroll
        for (int n = 0; n < 4; ++n)
          out[(size_t)row * 64 + n * 16 + lrow] = v[n] - mx - lg;
      }
    }
}

extern "C" void kernel_launch(void* const* d_in, const int* in_sizes, int n_in,
                              void* d_out, int out_size, void* d_ws,
                              size_t ws_size, hipStream_t stream) {
  const float* x  = (const float*)d_in[0];
  const int* eidx = (const int*)d_in[1];
  const float* W1 = (const float*)d_in[2];
  const float* b1 = (const float*)d_in[3];
  const float* W2 = (const float*)d_in[4];
  const float* b2 = (const float*)d_in[5];
  float* out = (float*)d_out;

  const int N = in_sizes[0] / 128;  // 50000
  const int E = in_sizes[1] / 2;    // 800000
  const int* src = eidx;
  const int* dst = eidx + E;

  const int nbuck = (N + 63) / 64;         // 782
  const int ntot = nbuck * NB_SORT;        // 200192
  const int nblk2 = (ntot + 1023) / 1024;  // 196

  // Workspace layout (disjoint agg1/agg2 so the fused kernel never writes
  // the region it is still reading): ~150 MB total.
  float* agg1   = (float*)d_ws;                     // N*128 f (25.6 MB)
  float* agg2   = agg1 + (size_t)N * 128;           // N*256 f (51.2 MB)
  float* h      = agg2 + (size_t)N * 256;           // N*256 f (51.2 MB)
  float4* npx   = (float4*)(h + (size_t)N * 256);
  float4* nph   = npx + N;
  int* S        = (int*)(nph + N);
  int* bsum     = S + ntot;
  int2* spair   = (int2*)(bsum + 256);
  signed char* qh = (signed char*)(spair + E);      // N*256 B (12.8 MB)
  unsigned short* W2h = (unsigned short*)(qh + (size_t)N * 256);
  unsigned short* W2l = W2h + 64 * 256;
  unsigned short* W1h = W2l + 64 * 256;
  unsigned short* W1l = W1h + 256 * 128;
  int2* epair   = (int2*)h;                              // overlap (6.4 MB)
  signed char* qx = (signed char*)(h + (size_t)N * 64);  // overlap (6.4 MB)

  // ---- pre-split W1/W2 into bf16 hi/lo planes (single launch) ----
  split_w2x<<<48, 256, 0, stream>>>(W2, W2h, W2l, W1, W1h, W1l);

  // ---- build dst-sorted edge list with LDS-only atomics ----
  hist_coarse<<<NB_SORT, 256, 0, stream>>>(dst, S, E, nbuck);
  scan_local<<<nblk2, 256, 0, stream>>>(S, bsum, ntot);
  scan_bsum<<<1, 256, 0, stream>>>(bsum, nblk2);
  add_bsum<<<(ntot + 255) / 256, 256, 0, stream>>>(S, bsum, ntot);
  scatter_coarse<<<NB_SORT, 256, 0, stream>>>(src, dst, S, epair, E, nbuck);
  fine_sort<<<nbuck, 256, 0, stream>>>(epair, S, spair, E, nbuck);

  // ---- layer 1 (D=128): batched conv, 128 edges per 256-thr block ----
  prep_x<<<(N + 3) / 4, 256, 0, stream>>>(x, qx, npx, agg1, N);
  conv_coop<128, 4><<<(E + 127) / 128, 256, 0, stream>>>(x, qx, npx, spair,
                                                         agg1, E);
  const int nwg1 = (N + 31) / 32;  // 1563
  gemm1_prep_fused<<<nwg1, 256, 0, stream>>>(agg1, W1h, W1l, b1, h, qh, nph,
                                             agg2, N, nwg1);

  // ---- layer 2 (D=256): batched conv, 64 edges per 256-thr block ----
  conv_coop<256, 4><<<(E + 63) / 64, 256, 0, stream>>>(h, qh, nph, spair,
                                                       agg2, E);
  gemm2_mfma_lsm<<<dim3((N + 127) / 128), 256, 0, stream>>>(agg2, W2h, W2l, b2,
                                                            out, N);
}

// Round 13
// 261.990 us; speedup vs baseline: 1.0168x; 1.0168x over previous
//
#include <hip/hip_runtime.h>
#include <math.h>

#define EPS 1e-8f
#define NB_SORT 256  // blocks in coarse sort phases

#if defined(__has_builtin)
#if __has_builtin(__builtin_amdgcn_sdot4)
#define HAVE_SDOT4 1
#endif
#endif

typedef __attribute__((ext_vector_type(8))) short bf16x8;
typedef __attribute__((ext_vector_type(4))) float f32x4;

__device__ __forceinline__ int sdot4i(int a, int b, int c) {
#ifdef HAVE_SDOT4
  return __builtin_amdgcn_sdot4(a, b, c, false);
#else
  return c + ((int)(signed char)(a)) * ((int)(signed char)(b)) +
         ((int)(signed char)(a >> 8)) * ((int)(signed char)(b >> 8)) +
         ((int)(signed char)(a >> 16)) * ((int)(signed char)(b >> 16)) +
         (a >> 24) * (b >> 24);
#endif
}

__device__ __forceinline__ float wave_reduce_sum(float v) {
#pragma unroll
  for (int off = 32; off > 0; off >>= 1)
    v += __shfl_xor(v, off, 64);
  return v;
}

__device__ __forceinline__ float wave_reduce_max(float v) {
#pragma unroll
  for (int off = 32; off > 0; off >>= 1)
    v = fmaxf(v, __shfl_xor(v, off, 64));
  return v;
}

__device__ __forceinline__ float dot4(float4 a, float4 b) {
  return a.x * b.x + a.y * b.y + a.z * b.z + a.w * b.w;
}

__device__ __forceinline__ int clampq(float q) {
  int i = (int)rintf(q);
  return i < -127 ? -127 : (i > 127 ? 127 : i);
}

// split fp32 into bf16 hi (truncate) + bf16 lo (exact residual, truncate)
// |x - (hi+lo)| <= 2^-16 |x|  (residual x-hi is exactly representable)
__device__ __forceinline__ void split_bf16(float x, unsigned int& hi,
                                           unsigned int& lo) {
  unsigned int u = __float_as_uint(x);
  hi = u >> 16;
  float hf = __uint_as_float(u & 0xFFFF0000u);
  float r = x - hf;
  lo = __float_as_uint(r) >> 16;
}

// split 8 fp32 (two float4) into bf16x8 hi/lo fragments
__device__ __forceinline__ void split8(float4 a0, float4 a1, bf16x8& th,
                                       bf16x8& tl) {
  unsigned int hh[8], ll[8];
  split_bf16(a0.x, hh[0], ll[0]); split_bf16(a0.y, hh[1], ll[1]);
  split_bf16(a0.z, hh[2], ll[2]); split_bf16(a0.w, hh[3], ll[3]);
  split_bf16(a1.x, hh[4], ll[4]); split_bf16(a1.y, hh[5], ll[5]);
  split_bf16(a1.z, hh[6], ll[6]); split_bf16(a1.w, hh[7], ll[7]);
#pragma unroll
  for (int j = 0; j < 8; ++j) {
    th[j] = (short)hh[j];
    tl[j] = (short)ll[j];
  }
}

// ============ CSR build: 2-level bucket sort, LDS atomics only ============
__global__ __launch_bounds__(256) void hist_coarse(const int* __restrict__ dst,
                                                   int* __restrict__ hist_blk,
                                                   int E, int nbuck) {
  __shared__ int lh[1024];
  int t = threadIdx.x, blk = blockIdx.x;
  for (int i = t; i < nbuck; i += 256) lh[i] = 0;
  __syncthreads();
  int ch = (E + NB_SORT - 1) / NB_SORT;
  int lo = blk * ch, hi = min(E, lo + ch);
  for (int e = lo + t; e < hi; e += 256) atomicAdd(&lh[dst[e] >> 6], 1);
  __syncthreads();
  for (int i = t; i < nbuck; i += 256) hist_blk[i * NB_SORT + blk] = lh[i];
}

__global__ __launch_bounds__(256) void scan_local(int* __restrict__ hist,
                                                  int* __restrict__ bsum,
                                                  int nb) {
  __shared__ int tsum[256];
  int t = threadIdx.x;
  int base = blockIdx.x * 1024 + t * 4;
  int v0 = 0, v1 = 0, v2 = 0, v3 = 0;
  if (base + 3 < nb) {
    int4 q = *(const int4*)&hist[base];
    v0 = q.x; v1 = q.y; v2 = q.z; v3 = q.w;
  } else {
    if (base + 0 < nb) v0 = hist[base + 0];
    if (base + 1 < nb) v1 = hist[base + 1];
    if (base + 2 < nb) v2 = hist[base + 2];
  }
  tsum[t] = v0 + v1 + v2 + v3;
  __syncthreads();
  for (int off = 1; off < 256; off <<= 1) {
    int u = 0;
    if (t >= off) u = tsum[t - off];
    __syncthreads();
    if (t >= off) tsum[t] += u;
    __syncthreads();
  }
  int excl = (t == 0) ? 0 : tsum[t - 1];
  int e0 = excl, e1 = excl + v0, e2 = e1 + v1, e3 = e2 + v2;
  if (base + 3 < nb) {
    *(int4*)&hist[base] = make_int4(e0, e1, e2, e3);
  } else {
    if (base + 0 < nb) hist[base + 0] = e0;
    if (base + 1 < nb) hist[base + 1] = e1;
    if (base + 2 < nb) hist[base + 2] = e2;
  }
  if (t == 255) bsum[blockIdx.x] = tsum[255];
}

__global__ __launch_bounds__(256) void scan_bsum(int* __restrict__ bsum,
                                                 int nblk) {
  __shared__ int sh[256];
  int t = threadIdx.x;
  sh[t] = (t < nblk) ? bsum[t] : 0;
  __syncthreads();
  for (int off = 1; off < 256; off <<= 1) {
    int u = 0;
    if (t >= off) u = sh[t - off];
    __syncthreads();
    if (t >= off) sh[t] += u;
    __syncthreads();
  }
  if (t < nblk) bsum[t] = (t == 0) ? 0 : sh[t - 1];
}

__global__ __launch_bounds__(256) void add_bsum(int* __restrict__ hist,
                                                const int* __restrict__ bsum,
                                                int nb) {
  int i = blockIdx.x * blockDim.x + threadIdx.x;
  if (i < nb) hist[i] += bsum[i >> 10];
}

__global__ __launch_bounds__(256) void scatter_coarse(
    const int* __restrict__ src, const int* __restrict__ dst,
    const int* __restrict__ S, int2* __restrict__ epair, int E, int nbuck) {
  __shared__ int lb[1024];
  int t = threadIdx.x, blk = blockIdx.x;
  for (int i = t; i < nbuck; i += 256) lb[i] = S[i * NB_SORT + blk];
  __syncthreads();
  int ch = (E + NB_SORT - 1) / NB_SORT;
  int lo = blk * ch, hi = min(E, lo + ch);
  for (int e = lo + t; e < hi; e += 256) {
    int d = dst[e];
    int pos = atomicAdd(&lb[d >> 6], 1);
    epair[pos] = make_int2(src[e], d);
  }
}

// emits fully dst-sorted (src,dst) pairs
__global__ __launch_bounds__(256) void fine_sort(
    const int2* __restrict__ epair, const int* __restrict__ S,
    int2* __restrict__ spair, int E, int nbuck) {
  __shared__ int fh[64];
  __shared__ int cur[64];
  int b = blockIdx.x, t = threadIdx.x;
  int bstart = S[b * NB_SORT];
  int bend = (b + 1 < nbuck) ? S[(b + 1) * NB_SORT] : E;
  if (t < 64) fh[t] = 0;
  __syncthreads();
  for (int e = bstart + t; e < bend; e += 256)
    atomicAdd(&fh[epair[e].y & 63], 1);
  __syncthreads();
  if (t < 64) {
    int v = fh[t];
    int incl = v;
#pragma unroll
    for (int off = 1; off < 64; off <<= 1) {
      int u = __shfl_up(incl, off, 64);
      if (t >= off) incl += u;
    }
    cur[t] = incl - v;
  }
  __syncthreads();
  for (int e = bstart + t; e < bend; e += 256) {
    int2 p = epair[e];
    int pos = atomicAdd(&cur[p.y & 63], 1);
    spair[bstart + pos] = p;
  }
}

// ============ prep_x: quantize + node props + self-loop agg init ==========
__global__ __launch_bounds__(256) void prep_x(const float* __restrict__ x,
                                              signed char* __restrict__ qx,
                                              float4* __restrict__ nprop,
                                              float* __restrict__ agg,
                                              int N) {
  int node = (int)((blockIdx.x * blockDim.x + threadIdx.x) >> 6);
  int lane = threadIdx.x & 63;
  if (node >= N) return;
  float2 v = *(const float2*)(x + (size_t)node * 128 + lane * 2);
  float ax = fabsf(v.x), ay = fabsf(v.y);
  float mx = wave_reduce_max(fmaxf(ax, ay));
  float l1 = wave_reduce_sum(ax + ay);
  float ss = wave_reduce_sum(v.x * v.x + v.y * v.y);
  float s = mx * (1.0f / 127.0f);
  float inv = (mx > 0.f) ? 127.0f / mx : 0.f;
  int q0 = clampq(v.x * inv), q1 = clampq(v.y * inv);
  unsigned short w = (unsigned short)((q0 & 0xff) | ((q1 & 0xff) << 8));
  ((unsigned short*)(qx + (size_t)node * 128))[lane] = w;
  float l1q = s * wave_reduce_sum((float)(abs(q0) + abs(q1)));
  bool sp = ss > 0.5f * fmaxf(ss, EPS);
  *(float2*)(agg + (size_t)node * 128 + lane * 2) =
      sp ? v : make_float2(0.f, 0.f);
  if (lane == 0)
    nprop[node] = make_float4(sqrtf(ss), s, fmaxf(l1, l1q), 0.f);
}

// ====== conv, group-cooperative + edge-batched: G = D/16 lanes per edge ====
// B=4 consecutive edge-groups per wave: all 2B qt-row loads (+nprop) issued
// back-to-back before any compute -> 4x the independent cache lines in
// flight per wave, 4x fewer blocks. Per-edge decision math is unchanged.
template <int D, int B>
__global__ __launch_bounds__(256) void conv_coop(
    const float* __restrict__ xf, const signed char* __restrict__ qt,
    const float4* __restrict__ nprop, const int2* __restrict__ spair,
    float* __restrict__ agg, int E) {
  constexpr int G = D / 16;    // lanes per edge: 8 (D=128) / 16 (D=256)
  constexpr int EPW = 64 / G;  // edges per wave per batch: 8 / 4
  constexpr int V = D / 64;    // fp32 elems per lane, full-wave path
  const int tid = threadIdx.x;
  const int lane = tid & 63;
  const int wv = tid >> 6;
  const int g = lane & (G - 1);
  const int sub = lane / G;
  const int w0 = (blockIdx.x * 4 + wv) * (EPW * B);
  int sA[B], dA[B];
  bool valA[B];
  float4 npsA[B], npdA[B];
  int4 qa[B], qb[B];
#pragma unroll
  for (int b = 0; b < B; ++b) {
    int e = w0 + b * EPW + sub;
    valA[b] = e < E;
    int2 p = spair[valA[b] ? e : (E - 1)];
    sA[b] = p.x;
    dA[b] = p.y;
  }
#pragma unroll
  for (int b = 0; b < B; ++b) {
    npsA[b] = nprop[sA[b]];
    npdA[b] = nprop[dA[b]];
    qa[b] = *(const int4*)(qt + (size_t)sA[b] * D + g * 16);
    qb[b] = *(const int4*)(qt + (size_t)dA[b] * D + g * 16);
  }
#pragma unroll
  for (int b = 0; b < B; ++b) {
    const int s = sA[b], d = dA[b];
    const float4 nps = npsA[b], npd = npdA[b];
    int id = 0;
    id = sdot4i(qa[b].x, qb[b].x, id);
    id = sdot4i(qa[b].y, qb[b].y, id);
    id = sdot4i(qa[b].z, qb[b].z, id);
    id = sdot4i(qa[b].w, qb[b].w, id);
#pragma unroll
    for (int off = G / 2; off > 0; off >>= 1) id += __shfl_xor(id, off, 64);
    float denom = fmaxf(nps.x * npd.x, EPS);
    float thr = 0.5f * denom;
    float approx = (nps.y * npd.y) * (float)id;
    float m =
        0.5002f * (nps.y * npd.z + npd.y * nps.z) + 2e-6f * denom + 1e-7f;
    bool maybe = valA[b] && (approx > thr - m);
    bool defp = maybe && (approx - m > thr);  // certainly above threshold
    bool amb = maybe && !defp;                // needs exact recompute
    unsigned long long defmask = __ballot(defp && g == 0);
    unsigned long long ambmask = __ballot(amb && g == 0);
    // ---- definite passes: add xf[src] into agg[dst], no dot needed ----
    while (defmask) {
      int ln = __ffsll((long long)defmask) - 1;
      defmask &= defmask - 1;
      int es = __shfl(s, ln);
      int ed = __shfl(d, ln);
      float* arow = agg + (size_t)ed * D + lane * V;
      if constexpr (V == 2) {
        float2 a = *(const float2*)(xf + (size_t)es * D + lane * 2);
        atomicAdd(&arow[0], a.x);
        atomicAdd(&arow[1], a.y);
      } else {
        float4 a = *(const float4*)(xf + (size_t)es * D + lane * 4);
        atomicAdd(&arow[0], a.x);
        atomicAdd(&arow[1], a.y);
        atomicAdd(&arow[2], a.z);
        atomicAdd(&arow[3], a.w);
      }
    }
    // ---- ambiguous: full-wave exact fp32 check (unchanged math) ----
    while (ambmask) {
      int ln = __ffsll((long long)ambmask) - 1;
      ambmask &= ambmask - 1;
      int es = __shfl(s, ln);
      int ed = __shfl(d, ln);
      float nsx = __shfl(nps.x, ln);
      float ndx = __shfl(npd.x, ln);
      float sv[V], dvv[V];
      if constexpr (V == 2) {
        float2 a = *(const float2*)(xf + (size_t)es * D + lane * 2);
        float2 bb = *(const float2*)(xf + (size_t)ed * D + lane * 2);
        sv[0] = a.x; sv[1] = a.y; dvv[0] = bb.x; dvv[1] = bb.y;
      } else {
        float4 a = *(const float4*)(xf + (size_t)es * D + lane * 4);
        float4 bb = *(const float4*)(xf + (size_t)ed * D + lane * 4);
        sv[0] = a.x; sv[1] = a.y; sv[2] = a.z; sv[3] = a.w;
        dvv[0] = bb.x; dvv[1] = bb.y; dvv[2] = bb.z; dvv[3] = bb.w;
      }
      float dx = 0.f;
#pragma unroll
      for (int q = 0; q < V; ++q) dx += sv[q] * dvv[q];
      dx = wave_reduce_sum(dx);
      if (dx > 0.5f * fmaxf(nsx * ndx, EPS)) {
        float* arow = agg + (size_t)ed * D + lane * V;
#pragma unroll
        for (int q = 0; q < V; ++q) atomicAdd(&arow[q], sv[q]);
      }
    }
  }
}

// ---- pre-split BOTH weight matrices into bf16 hi/lo planes (one launch) ---
__global__ __launch_bounds__(256) void split_w2x(
    const float* __restrict__ W2, unsigned short* __restrict__ W2h,
    unsigned short* __restrict__ W2l, const float* __restrict__ W1,
    unsigned short* __restrict__ W1h, unsigned short* __restrict__ W1l) {
  int blk = blockIdx.x;
  const float* W;
  unsigned short *Wh, *Wl;
  int i;
  if (blk < 16) {  // W2: 64*256/4 = 4096 float4 = 16 blocks
    W = W2; Wh = W2h; Wl = W2l;
    i = blk * 256 + threadIdx.x;
  } else {  // W1: 256*128/4 = 8192 float4 = 32 blocks
    W = W1; Wh = W1h; Wl = W1l;
    i = (blk - 16) * 256 + threadIdx.x;
  }
  float4 w = ((const float4*)W)[i];
  unsigned int h0, h1, h2, h3, l0, l1, l2, l3;
  split_bf16(w.x, h0, l0); split_bf16(w.y, h1, l1);
  split_bf16(w.z, h2, l2); split_bf16(w.w, h3, l3);
  ((uint2*)Wh)[i] = make_uint2(h0 | (h1 << 16), h2 | (h3 << 16));
  ((uint2*)Wl)[i] = make_uint2(l0 | (l1 << 16), l2 | (l3 << 16));
}

// ------ GEMM1 + prep_h FUSED, coalesced vectorized epilogue ----------------
// Round-10 configuration (measured best: 54.9us, WRITE=113.3MB). NT stores
// reverted: round-12 within-probe A/B showed they cost +4us and +3MB write
// (NT bypasses L2 write-combining on this mixed stream).
__global__ __launch_bounds__(256) void gemm1_prep_fused(
    const float* __restrict__ A, const unsigned short* __restrict__ Wh,
    const unsigned short* __restrict__ Wl, const float* __restrict__ bias,
    float* __restrict__ h, signed char* __restrict__ qh,
    float4* __restrict__ nprop, float* __restrict__ agg2, int M, int nwg) {
  constexpr int K = 128, NN = 256, PAD = 68;
  // bijective XCD swizzle (m204)
  int orig = blockIdx.x;
  int qq = nwg >> 3, rr8 = nwg & 7;
  int xcd = orig & 7, loc = orig >> 3;
  int wg = (xcd < rr8 ? xcd * (qq + 1) : rr8 * (qq + 1) + (xcd - rr8) * qq) + loc;
  const int tid = threadIdx.x;
  const int lane = tid & 63;
  const int wv = tid >> 6;  // wave = 64-col slice
  const int lrow = lane & 15, kg = lane >> 4;
  const int r0 = wg * 32;
  const int n0 = wv * 64;
  __shared__ float stage[4][32][PAD];  // 34816 B, per-wave 32x64 slice
  __shared__ float4 red[32][4];        // per-row per-wave (mx, ss, l1, -)
  __shared__ float4 state[32];         // per-row (ss, s, inv, l1)
  __shared__ float red2[32][4];        // per-row per-wave sum|q|

  f32x4 acc[2][4] = {};
  for (int k0 = 0; k0 < K; k0 += 32) {
    bf16x8 ah[2], al[2];
#pragma unroll
    for (int m = 0; m < 2; ++m) {
      int row = r0 + m * 16 + lrow;  // rows < 50016 stay inside ws
      const float* ap = A + (size_t)row * K + k0 + kg * 8;
      float4 a0 = *(const float4*)ap;
      float4 a1 = *(const float4*)(ap + 4);
      split8(a0, a1, ah[m], al[m]);
    }
    bf16x8 bh[4], bl[4];
#pragma unroll
    for (int n = 0; n < 4; ++n) {
      int wrow = n0 + n * 16 + lrow;
      bh[n] = *(const bf16x8*)&Wh[(size_t)wrow * K + k0 + kg * 8];
      bl[n] = *(const bf16x8*)&Wl[(size_t)wrow * K + k0 + kg * 8];
    }
#pragma unroll
    for (int m = 0; m < 2; ++m)
#pragma unroll
      for (int n = 0; n < 4; ++n) {
        acc[m][n] = __builtin_amdgcn_mfma_f32_16x16x32_bf16(ah[m], bh[n],
                                                            acc[m][n], 0, 0, 0);
        acc[m][n] = __builtin_amdgcn_mfma_f32_16x16x32_bf16(ah[m], bl[n],
                                                            acc[m][n], 0, 0, 0);
        acc[m][n] = __builtin_amdgcn_mfma_f32_16x16x32_bf16(al[m], bh[n],
                                                            acc[m][n], 0, 0, 0);
      }
  }

  // ---- bias + relu in place ----
  float bv[4];
#pragma unroll
  for (int n = 0; n < 4; ++n) bv[n] = bias[n0 + n * 16 + lrow];
#pragma unroll
  for (int m = 0; m < 2; ++m)
#pragma unroll
    for (int n = 0; n < 4; ++n)
#pragma unroll
      for (int r = 0; r < 4; ++r)
        acc[m][n][r] = fmaxf(acc[m][n][r] + bv[n], 0.f);

  // ---- per-row partials within wave (row = m*16 + kg*4 + r) ----
#pragma unroll
  for (int m = 0; m < 2; ++m)
#pragma unroll
    for (int r = 0; r < 4; ++r) {
      float mx = 0.f, ss = 0.f, l1 = 0.f;
#pragma unroll
      for (int n = 0; n < 4; ++n) {
        float v = acc[m][n][r];
        float a = fabsf(v);
        mx = fmaxf(mx, a);
        ss += v * v;
        l1 += a;
      }
#pragma unroll
      for (int off = 1; off < 16; off <<= 1) {
        mx = fmaxf(mx, __shfl_xor(mx, off, 64));
        ss += __shfl_xor(ss, off, 64);
        l1 += __shfl_xor(l1, off, 64);
      }
      if (lrow == 0) red[m * 16 + kg * 4 + r][wv] = make_float4(mx, ss, l1, 0.f);
    }

  // ---- stage the wave's 32x64 slice into LDS (2-way banks = free) ----
#pragma unroll
  for (int m = 0; m < 2; ++m)
#pragma unroll
    for (int n = 0; n < 4; ++n)
#pragma unroll
      for (int r = 0; r < 4; ++r)
        stage[wv][m * 16 + kg * 4 + r][n * 16 + lrow] = acc[m][n][r];

  __syncthreads();
  if (tid < 32) {
    float mx = 0.f, ss = 0.f, l1 = 0.f;
#pragma unroll
    for (int w = 0; w < 4; ++w) {
      float4 p = red[tid][w];
      mx = fmaxf(mx, p.x);
      ss += p.y;
      l1 += p.z;
    }
    float s = mx * (1.0f / 127.0f);
    float inv = (mx > 0.f) ? 127.0f / mx : 0.f;
    state[tid] = make_float4(ss, s, inv, l1);
  }
  __syncthreads();

  // ---- coalesced vectorized stores: 4 rows x contiguous 256B per instr ----
  {
    const int rr = lane >> 4;   // row within quad
    const int cc = lane & 15;   // col group (4 floats)
#pragma unroll
    for (int rb = 0; rb < 8; ++rb) {
      const int row = rb * 4 + rr;
      const int grow = r0 + row;
      const bool ok = grow < M;
      float4 st = state[row];
      float inv = st.z;
      float spm = (st.x > 0.5f * fmaxf(st.x, EPS)) ? 1.0f : 0.0f;
      float4 v4 = *(const float4*)&stage[wv][row][cc * 4];
      int q0 = clampq(v4.x * inv), q1 = clampq(v4.y * inv);
      int q2 = clampq(v4.z * inv), q3 = clampq(v4.w * inv);
      int sq = abs(q0) + abs(q1) + abs(q2) + abs(q3);
#pragma unroll
      for (int off = 1; off < 16; off <<= 1) sq += __shfl_xor(sq, off, 64);
      if (ok) {
        int col = n0 + cc * 4;
        *(float4*)&h[(size_t)grow * NN + col] = v4;
        float4 a4 = make_float4(spm * v4.x, spm * v4.y, spm * v4.z, spm * v4.w);
        *(float4*)&agg2[(size_t)grow * NN + col] = a4;
        int packed = (q0 & 0xff) | ((q1 & 0xff) << 8) | ((q2 & 0xff) << 16) |
                     (q3 << 24);
        *(int*)&qh[(size_t)grow * NN + col] = packed;
      }
      if (cc == 0) red2[row][wv] = (float)sq;
    }
  }
  __syncthreads();
  if (tid < 32) {
    float sq = 0.f;
#pragma unroll
    for (int w = 0; w < 4; ++w) sq += red2[tid][w];
    float4 st = state[tid];
    float l1q = st.y * sq;
    int grow = r0 + tid;
    if (grow < M)
      nprop[grow] = make_float4(sqrtf(st.x), st.y, fmaxf(st.w, l1q), 0.f);
  }
}

// ------ GEMM2 via MFMA, LDS-free, fused log_softmax ------------------------
__global__ __launch_bounds__(256) void gemm2_mfma_lsm(
    const float* __restrict__ A, const unsigned short* __restrict__ Wh,
    const unsigned short* __restrict__ Wl, const float* __restrict__ bias,
    float* __restrict__ out, int M) {
  constexpr int K = 256;
  const int tid = threadIdx.x;
  const int lane = tid & 63;
  const int wv = tid >> 6;
  const int lrow = lane & 15, kg = lane >> 4;
  const int r0 = blockIdx.x * 128 + wv * 32;  // wave's first row
  f32x4 acc[2][4] = {};

  for (int k0 = 0; k0 < K; k0 += 32) {
    bf16x8 ah[2], al[2];
#pragma unroll
    for (int m = 0; m < 2; ++m) {
      int row = r0 + m * 16 + lrow;  // rows up to 50047 stay inside ws
      const float* ap = A + (size_t)row * K + k0 + kg * 8;
      float4 a0 = *(const float4*)ap;
      float4 a1 = *(const float4*)(ap + 4);
      split8(a0, a1, ah[m], al[m]);
    }
    bf16x8 bh[4], bl[4];
#pragma unroll
    for (int n = 0; n < 4; ++n) {
      int wrow = n * 16 + lrow;
      bh[n] = *(const bf16x8*)&Wh[(size_t)wrow * K + k0 + kg * 8];
      bl[n] = *(const bf16x8*)&Wl[(size_t)wrow * K + k0 + kg * 8];
    }
#pragma unroll
    for (int m = 0; m < 2; ++m)
#pragma unroll
      for (int n = 0; n < 4; ++n) {
        acc[m][n] = __builtin_amdgcn_mfma_f32_16x16x32_bf16(ah[m], bh[n],
                                                            acc[m][n], 0, 0, 0);
        acc[m][n] = __builtin_amdgcn_mfma_f32_16x16x32_bf16(ah[m], bl[n],
                                                            acc[m][n], 0, 0, 0);
        acc[m][n] = __builtin_amdgcn_mfma_f32_16x16x32_bf16(al[m], bh[n],
                                                            acc[m][n], 0, 0, 0);
      }
  }

  float bv[4];
#pragma unroll
  for (int n = 0; n < 4; ++n) bv[n] = bias[n * 16 + lrow];
#pragma unroll
  for (int m = 0; m < 2; ++m)
#pragma unroll
    for (int r = 0; r < 4; ++r) {
      int row = r0 + m * 16 + kg * 4 + r;
      float v[4];
      float mx = -1e30f;
#pragma unroll
      for (int n = 0; n < 4; ++n) {
        v[n] = acc[m][n][r] + bv[n];
        mx = fmaxf(mx, v[n]);
      }
#pragma unroll
      for (int off = 8; off > 0; off >>= 1)
        mx = fmaxf(mx, __shfl_xor(mx, off, 64));
      float s = 0.f;
#pragma unroll
      for (int n = 0; n < 4; ++n) s += expf(v[n] - mx);
#pragma unroll
      for (int off = 8; off > 0; off >>= 1) s += __shfl_xor(s, off, 64);
      float lg = logf(s);
      if (row < M) {
#pragma unroll
        for (int n = 0; n < 4; ++n)
          out[(size_t)row * 64 + n * 16 + lrow] = v[n] - mx - lg;
      }
    }
}

extern "C" void kernel_launch(void* const* d_in, const int* in_sizes, int n_in,
                              void* d_out, int out_size, void* d_ws,
                              size_t ws_size, hipStream_t stream) {
  const float* x  = (const float*)d_in[0];
  const int* eidx = (const int*)d_in[1];
  const float* W1 = (const float*)d_in[2];
  const float* b1 = (const float*)d_in[3];
  const float* W2 = (const float*)d_in[4];
  const float* b2 = (const float*)d_in[5];
  float* out = (float*)d_out;

  const int N = in_sizes[0] / 128;  // 50000
  const int E = in_sizes[1] / 2;    // 800000
  const int* src = eidx;
  const int* dst = eidx + E;

  const int nbuck = (N + 63) / 64;         // 782
  const int ntot = nbuck * NB_SORT;        // 200192
  const int nblk2 = (ntot + 1023) / 1024;  // 196

  // Workspace layout (disjoint agg1/agg2 so the fused kernel never writes
  // the region it is still reading): ~150 MB total.
  float* agg1   = (float*)d_ws;                     // N*128 f (25.6 MB)
  float* agg2   = agg1 + (size_t)N * 128;           // N*256 f (51.2 MB)
  float* h      = agg2 + (size_t)N * 256;           // N*256 f (51.2 MB)
  float4* npx   = (float4*)(h + (size_t)N * 256);
  float4* nph   = npx + N;
  int* S        = (int*)(nph + N);
  int* bsum     = S + ntot;
  int2* spair   = (int2*)(bsum + 256);
  signed char* qh = (signed char*)(spair + E);      // N*256 B (12.8 MB)
  unsigned short* W2h = (unsigned short*)(qh + (size_t)N * 256);
  unsigned short* W2l = W2h + 64 * 256;
  unsigned short* W1h = W2l + 64 * 256;
  unsigned short* W1l = W1h + 256 * 128;
  int2* epair   = (int2*)h;                              // overlap (6.4 MB)
  signed char* qx = (signed char*)(h + (size_t)N * 64);  // overlap (6.4 MB)

  // ---- pre-split W1/W2 into bf16 hi/lo planes (single launch) ----
  split_w2x<<<48, 256, 0, stream>>>(W2, W2h, W2l, W1, W1h, W1l);

  // ---- build dst-sorted edge list with LDS-only atomics ----
  hist_coarse<<<NB_SORT, 256, 0, stream>>>(dst, S, E, nbuck);
  scan_local<<<nblk2, 256, 0, stream>>>(S, bsum, ntot);
  scan_bsum<<<1, 256, 0, stream>>>(bsum, nblk2);
  add_bsum<<<(ntot + 255) / 256, 256, 0, stream>>>(S, bsum, ntot);
  scatter_coarse<<<NB_SORT, 256, 0, stream>>>(src, dst, S, epair, E, nbuck);
  fine_sort<<<nbuck, 256, 0, stream>>>(epair, S, spair, E, nbuck);

  // ---- layer 1 (D=128): batched conv, 128 edges per 256-thr block ----
  prep_x<<<(N + 3) / 4, 256, 0, stream>>>(x, qx, npx, agg1, N);
  conv_coop<128, 4><<<(E + 127) / 128, 256, 0, stream>>>(x, qx, npx, spair,
                                                         agg1, E);
  const int nwg1 = (N + 31) / 32;  // 1563
  gemm1_prep_fused<<<nwg1, 256, 0, stream>>>(agg1, W1h, W1l, b1, h, qh, nph,
                                             agg2, N, nwg1);

  // ---- layer 2 (D=256): batched conv, 64 edges per 256-thr block ----
  conv_coop<256, 4><<<(E + 63) / 64, 256, 0, stream>>>(h, qh, nph, spair,
                                                       agg2, E);
  gemm2_mfma_lsm<<<dim3((N + 127) / 128), 256, 0, stream>>>(agg2, W2h, W2l, b2,
                                                            out, N);
}